// Round 11
// baseline (191.643 us; speedup 1.0000x reference)
//
#include <hip/hip_runtime.h>
#include <hip/hip_bf16.h>

using bf16 = __hip_bfloat16;
using v8s = __attribute__((ext_vector_type(8))) short;   // MFMA A/B frag: 8 bf16
using v4f = __attribute__((ext_vector_type(4))) float;   // MFMA C/D frag

// Problem constants (from reference)
constexpr int kB = 4, kM = 64;
constexpr int kN2 = 512, kN1 = 2048, kN0 = 8192;
constexpr int kC2 = 256, kC1 = 128, kC0 = 64;

__device__ __forceinline__ float bs2f(unsigned short u) {
    return __uint_as_float((unsigned)u << 16);
}
__device__ __forceinline__ unsigned short f2bs(float f) {  // RNE fp32->bf16
    unsigned u = __float_as_uint(f);
    u += 0x7FFFu + ((u >> 16) & 1u);
    return (unsigned short)(u >> 16);
}
__device__ __forceinline__ float rdIn(const void* p, long i, int f32) {
    return f32 ? ((const float*)p)[i] : bs2f(((const unsigned short*)p)[i]);
}
__device__ __forceinline__ unsigned short rdBS(const void* p, long i, int f32) {
    return f32 ? f2bs(((const float*)p)[i]) : ((const unsigned short*)p)[i];
}
// load 8 consecutive elements as fp32 (16B-aligned offsets only)
__device__ __forceinline__ void ld8(const void* p, long off, int f32, float v[8]) {
    if (f32) {
        const float* fp = (const float*)p + off;
        float4 a = *(const float4*)fp;
        float4 b = *(const float4*)(fp + 4);
        v[0] = a.x; v[1] = a.y; v[2] = a.z; v[3] = a.w;
        v[4] = b.x; v[5] = b.y; v[6] = b.z; v[7] = b.w;
    } else {
        const unsigned short* hp = (const unsigned short*)p + off;
        uint4 u = *(const uint4*)hp;
        unsigned w[4] = {u.x, u.y, u.z, u.w};
        #pragma unroll
        for (int i = 0; i < 4; i++) {
            v[2 * i]     = bs2f((unsigned short)(w[i] & 0xFFFFu));
            v[2 * i + 1] = bs2f((unsigned short)(w[i] >> 16));
        }
    }
}
__device__ __forceinline__ uint4 pack8(const unsigned short o[8]) {
    uint4 u;
    u.x = (unsigned)o[0] | ((unsigned)o[1] << 16);
    u.y = (unsigned)o[2] | ((unsigned)o[3] << 16);
    u.z = (unsigned)o[4] | ((unsigned)o[5] << 16);
    u.w = (unsigned)o[6] | ((unsigned)o[7] << 16);
    return u;
}

__global__ void fpno_guard(float code, float* __restrict__ out) {
    if (threadIdx.x == 0) out[0] = code;
}

// ===========================================================================
// PHASE 1 (one launch, 512 thr): wconv(frag-order) | gates | layer-1 kNN |
// bin x2 | tail.  (unchanged from round 10 — proven)
// ===========================================================================
__global__ __launch_bounds__(512) void fpno_p1(
    const unsigned int* __restrict__ posW,
    const void* __restrict__ pos,
    const void* __restrict__ pos1,
    const void* __restrict__ pos0,
    const void* __restrict__ W0a, const void* __restrict__ W0b,
    const void* __restrict__ W1a, const void* __restrict__ W1b,
    const void* __restrict__ par,
    const void* __restrict__ Wp0, const void* __restrict__ bp0,
    const void* __restrict__ Wp1, const void* __restrict__ bp1,
    const int* __restrict__ bt0,
    int* __restrict__ flag, unsigned short* __restrict__ WT,
    float* __restrict__ g0, float* __restrict__ g1,
    int* __restrict__ i1d, float* __restrict__ w1d,
    float4* __restrict__ ptsG, int* __restrict__ cstG,
    float4* __restrict__ ptsT, int* __restrict__ cstT,
    float* __restrict__ out) {
    #pragma clang fp contract(off)
    __shared__ __align__(16) char smem[20480];
    __shared__ int sflg[2];
    const int b = blockIdx.x, tid = threadIdx.x;

    if (tid == 0) { sflg[0] = 0; sflg[1] = 0; }
    __syncthreads();
    {
        unsigned lo = posW[tid] & 0xFFFFu;   // words 0..511
        int bad = 0, nz = 0;
        if (lo != 0u) { nz = 1; if ((lo & 0x8000u) || lo > 0x3F80u) bad = 1; }
        if (bad) sflg[0] = 1;
        if (nz) sflg[1] = 1;
    }
    __syncthreads();
    const int f32 = (sflg[0] || !sflg[1]) ? 1 : 0;
    if (b == 0 && tid == 0) *flag = f32;

    if (b < 320) {
        // ---- weight convert to FRAGMENT-ordered bf16 (WTf) ----
        int id = b * 512 + tid;
        const void* src; int N; int base, local;
        if      (id < 98304)  { src = W0a; N = 256; base = 0;      local = id; }
        else if (id < 131072) { src = W0b; N = 128; base = 98304;  local = id - 98304; }
        else if (id < 155648) { src = W1a; N = 128; base = 131072; local = id - 131072; }
        else                  { src = W1b; N = 64;  base = 155648; local = id - 155648; }
        int NT = N >> 4;
        int e = local & 7;
        int l = (local >> 3) & 63;
        int rest = local >> 9;
        int t = rest % NT;
        int kc = rest / NT;
        int n = t * 16 + (l & 15);
        int k = kc * 32 + ((l >> 4) << 3) + e;
        WT[base + local] = rdBS(src, (long)k * N + n, f32);
    } else if (b < 322) {
        int id = (b - 320) * 512 + tid;
        if (id < kB * 128) {
            int bb = id / 128, n = id % 128;
            float a = rdIn(bp0, n, f32);
            for (int m = 0; m < kM; m++)
                a += rdIn(par, bb * kM + m, f32) * rdIn(Wp0, m * 128 + n, f32);
            g0[id] = tanhf(a);
        } else if (id < kB * 128 + kB * 64) {
            int id2 = id - kB * 128;
            int bb = id2 / 64, n = id2 % 64;
            float a = rdIn(bp1, n, f32);
            for (int m = 0; m < kM; m++)
                a += rdIn(par, bb * kM + m, f32) * rdIn(Wp1, m * 64 + n, f32);
            g1[id2] = tanhf(a);
        }
    } else if (b < 450) {
        constexpr int NS = kN2;
        float4* sp = (float4*)smem;
        float*  cd = (float*)(smem + 8192);
        int*    ci = (int*)(smem + 14336);
        const int blk = b - 322;
        const int tLoc = tid >> 3;
        const int spl  = tid & 7;
        const int tGlob = blk * 64 + tLoc;
        const int smp = tGlob / kN1;
        for (int i = tid; i < NS; i += 512) {
            long bb = (long)(smp * NS + i) * 3;
            sp[i] = make_float4(rdIn(pos, bb, f32), rdIn(pos, bb + 1, f32),
                                rdIn(pos, bb + 2, f32), 0.f);
        }
        __syncthreads();
        long tb = (long)tGlob * 3;
        float px = rdIn(pos1, tb, f32), py = rdIn(pos1, tb + 1, f32),
              pz = rdIn(pos1, tb + 2, f32);
        float d0 = 1e30f, d1 = 1e30f, d2 = 1e30f;
        int i0 = 0x7FFFFFFF, i1 = 0x7FFFFFFF, i2 = 0x7FFFFFFF;
        for (int j = spl; j < NS; j += 8) {
            float4 s = sp[j];
            float dx = px - s.x, dy = py - s.y, dz = pz - s.z;
            float d = ((dx * dx) + (dy * dy)) + (dz * dz);
            bool l0 = d < d0, l1 = d < d1, l2 = d < d2;
            float nd2 = l1 ? d1 : (l2 ? d : d2);
            int   ni2 = l1 ? i1 : (l2 ? j : i2);
            float nd1 = l0 ? d0 : (l1 ? d : d1);
            int   ni1 = l0 ? i0 : (l1 ? j : i1);
            float nd0 = l0 ? d : d0;
            int   ni0 = l0 ? j : i0;
            d2 = nd2; i2 = ni2; d1 = nd1; i1 = ni1; d0 = nd0; i0 = ni0;
        }
        cd[tid * 3 + 0] = d0; ci[tid * 3 + 0] = i0;
        cd[tid * 3 + 1] = d1; ci[tid * 3 + 1] = i1;
        cd[tid * 3 + 2] = d2; ci[tid * 3 + 2] = i2;
        __syncthreads();
        if (spl == 0) {
            float b0 = 1e30f, b1 = 1e30f, b2 = 1e30f;
            int k0 = 0x7FFFFFFF, k1 = 0x7FFFFFFF, k2 = 0x7FFFFFFF;
            int qb = tLoc * 24;
            for (int q = 0; q < 24; q++) {
                float d = cd[qb + q];
                int i = ci[qb + q];
                if ((d < b2) || (d == b2 && i < k2)) {
                    if ((d < b1) || (d == b1 && i < k1)) {
                        b2 = b1; k2 = k1;
                        if ((d < b0) || (d == b0 && i < k0)) { b1 = b0; k1 = k0; b0 = d; k0 = i; }
                        else                                  { b1 = d;  k1 = i; }
                    } else { b2 = d; k2 = i; }
                }
            }
            float wa = 1.f / fmaxf(b0, 1e-16f);
            float wb = 1.f / fmaxf(b1, 1e-16f);
            float wc = 1.f / fmaxf(b2, 1e-16f);
            float s = wa + wb + wc;
            i1d[tGlob * 3 + 0] = smp * NS + k0;
            i1d[tGlob * 3 + 1] = smp * NS + k1;
            i1d[tGlob * 3 + 2] = smp * NS + k2;
            w1d[tGlob * 3 + 0] = wa / s;
            w1d[tGlob * 3 + 1] = wb / s;
            w1d[tGlob * 3 + 2] = wc / s;
        }
    } else if (b < 458) {
        constexpr int G3 = 512;
        int* cnt = (int*)smem;
        int* sc  = cnt + G3;
        int* cur = sc + G3;
        const bool srcSide = (b < 454);
        const int smp = srcSide ? (b - 450) : (b - 454);
        const int NSb = srcSide ? kN1 : kN0;
        const int PPT = NSb / 512;
        const void* P = srcSide ? pos1 : pos0;
        float4* pts = srcSide ? ptsG : ptsT;
        int* cstart = srcSide ? cstG : cstT;
        for (int i = tid; i < G3; i += 512) cnt[i] = 0;
        __syncthreads();
        float4 p[16]; int cl[16];
        for (int r = 0; r < PPT; r++) {
            int j = r * 512 + tid;
            long bb = ((long)smp * NSb + j) * 3;
            float x = rdIn(P, bb, f32), y = rdIn(P, bb + 1, f32), z = rdIn(P, bb + 2, f32);
            int cx = min(7, max(0, (int)(x * 8.f)));
            int cy = min(7, max(0, (int)(y * 8.f)));
            int cz = min(7, max(0, (int)(z * 8.f)));
            cl[r] = (cz * 8 + cy) * 8 + cx;
            p[r] = make_float4(x, y, z, __int_as_float(j));
            atomicAdd(&cnt[cl[r]], 1);
        }
        __syncthreads();
        int v = cnt[tid];
        sc[tid] = v;
        __syncthreads();
        for (int ofs = 1; ofs < G3; ofs <<= 1) {
            int t = 0;
            if (tid >= ofs) t = sc[tid - ofs];
            __syncthreads();
            sc[tid] += t;
            __syncthreads();
        }
        {
            int st = sc[tid] - v;
            cur[tid] = st;
            cstart[smp * (G3 + 1) + tid] = st;
        }
        if (tid == 0) cstart[smp * (G3 + 1) + G3] = NSb;
        __syncthreads();
        for (int r = 0; r < PPT; r++) {
            int slot = atomicAdd(&cur[cl[r]], 1);
            pts[(long)smp * NSb + slot] = p[r];
        }
    } else {
        int id = (b - 458) * 512 + tid;
        const int nX = kB * kN0 * kC0;
        const int nP = kB * kN0 * 3;
        if (id < nP) out[nX + id] = rdIn(pos0, id, f32);
        else         out[nX + id] = (float)bt0[id - nP];
    }
}

// ===========================================================================
// PHASE 2 (one launch, 256 thr), co-scheduled:
//   blocks [0,512):     fused layer-1 MLP, 16-row slabs + WTf (round-10 proven).
//   blocks [512,1536):  layer-2 grid kNN — ROUND-11 CHANGE: box-staged union
//     scan. The block's 32 cell-sorted targets share a home-cell bounding box;
//     box±1 (clamped) ⊇ every target's rings 0-1. Stage all box points into
//     LDS (cap 384 = 6 KB) via contiguous (Z,Y)-row segments, then scan the
//     staged SUPERSET per target with 8 split lanes (pure LDS compute — was
//     27 per-cell global-latency scans, 92% stall at 29us standalone).
//     Exact: superset scan of rings 0-1 is exact under (d,idx)-lex order;
//     ring s>=2 loop SKIPS box cells (already scanned; rescan would dup) and
//     its break bound stays valid (rings 0..s-1 always fully covered).
//     Oversized boxes (cy/cz wrap, ~3%) -> byte-identical proven fallback.
// ===========================================================================
__global__ __launch_bounds__(256) void fpno_p2(
    const void* __restrict__ x, const void* __restrict__ xs1,
    const unsigned short* __restrict__ WTf,
    const void* __restrict__ b0a, const void* __restrict__ b0b,
    const float* __restrict__ g0,
    const int* __restrict__ i1d, const float* __restrict__ w1d,
    const float4* __restrict__ ptsG, const int* __restrict__ cstG,
    const float4* __restrict__ ptsT,
    const int* __restrict__ flagp,
    unsigned short* __restrict__ X1,
    int* __restrict__ i0d, float* __restrict__ w0d) {
    #pragma clang fp contract(off)
    __shared__ __align__(16) char smem[21504];
    const int tid = threadIdx.x;

    if (blockIdx.x < 512) {
        // ================= fused layer-1 MLP, 16-row slab =================
        constexpr int LDX = 392;   // 384 + 8 pad (halves)
        constexpr int LDH = 264;   // 256 + 8 pad
        const int f32 = *flagp;
        unsigned short* XC = (unsigned short*)smem;            // 12544 B
        unsigned short* Hs = (unsigned short*)(smem + 12544);  // 8448 B
        const int bm = blockIdx.x;

        for (int u = tid; u < 768; u += 256) {
            int row = u / 48, c0 = (u % 48) * 8;
            int gr = bm * 16 + row;
            unsigned short o[8];
            if (c0 < kC2) {
                int j0 = i1d[gr * 3 + 0], j1 = i1d[gr * 3 + 1], j2 = i1d[gr * 3 + 2];
                float ww0 = w1d[gr * 3 + 0], ww1 = w1d[gr * 3 + 1], ww2 = w1d[gr * 3 + 2];
                float a0[8], a1[8], a2[8];
                ld8(x, (long)j0 * kC2 + c0, f32, a0);
                ld8(x, (long)j1 * kC2 + c0, f32, a1);
                ld8(x, (long)j2 * kC2 + c0, f32, a2);
                #pragma unroll
                for (int j = 0; j < 8; j++)
                    o[j] = f2bs(ww0 * a0[j] + ww1 * a1[j] + ww2 * a2[j]);
            } else {
                float s8[8];
                ld8(xs1, (long)gr * kC1 + (c0 - kC2), f32, s8);
                #pragma unroll
                for (int j = 0; j < 8; j++) o[j] = f2bs(s8[j]);
            }
            *(uint4*)&XC[row * LDX + c0] = pack8(o);
        }
        __syncthreads();

        const int lane = tid & 63, w = tid >> 6;
        const int l16 = lane & 15, quad = lane >> 4;
        v4f acc[4];
        #pragma unroll
        for (int t = 0; t < 4; t++) acc[t] = (v4f){0.f, 0.f, 0.f, 0.f};
        #pragma unroll 1
        for (int k0 = 0; k0 < 384; k0 += 32) {
            const v8s a = *(const v8s*)&XC[l16 * LDX + k0 + quad * 8];
            int kc = k0 >> 5;
            #pragma unroll
            for (int t = 0; t < 4; t++) {
                int tg = w * 4 + t;                 // col-tile 0..15 (N=256)
                const v8s bfr = *(const v8s*)&WTf[(((kc * 16 + tg) << 6) + lane) * 8];
                acc[t] = __builtin_amdgcn_mfma_f32_16x16x32_bf16(a, bfr, acc[t], 0, 0, 0);
            }
        }
        #pragma unroll
        for (int t = 0; t < 4; t++) {
            int c = (w * 4 + t) * 16 + l16;
            float bb = rdIn(b0a, c, f32);
            #pragma unroll
            for (int i = 0; i < 4; i++)
                Hs[(quad * 4 + i) * LDH + c] = f2bs(tanhf(acc[t][i] + bb));
        }
        __syncthreads();

        v4f acc2[2];
        #pragma unroll
        for (int t = 0; t < 2; t++) acc2[t] = (v4f){0.f, 0.f, 0.f, 0.f};
        #pragma unroll 1
        for (int k0 = 0; k0 < 256; k0 += 32) {
            const v8s a = *(const v8s*)&Hs[l16 * LDH + k0 + quad * 8];
            int kc = k0 >> 5;
            #pragma unroll
            for (int t = 0; t < 2; t++) {
                int tg = w * 2 + t;                 // col-tile 0..7 (N=128)
                const v8s bfr = *(const v8s*)&WTf[98304 + (((kc * 8 + tg) << 6) + lane) * 8];
                acc2[t] = __builtin_amdgcn_mfma_f32_16x16x32_bf16(a, bfr, acc2[t], 0, 0, 0);
            }
        }
        #pragma unroll
        for (int t = 0; t < 2; t++) {
            int c = (w * 2 + t) * 16 + l16;
            float bb = rdIn(b0b, c, f32);
            #pragma unroll
            for (int i = 0; i < 4; i++) {
                int gr = bm * 16 + quad * 4 + i;
                float v = tanhf(acc2[t][i] + bb) * g0[(gr >> 11) * 128 + c];
                X1[(long)gr * 128 + c] = f2bs(v);
            }
        }
    } else {
        // ================= layer-2 grid kNN: box-staged union scan =================
        constexpr int NS = kN1, NT = kN0, G = 8, SPLIT = 8;
        constexpr int G3 = G * G * G;
        constexpr float h = 1.0f / (float)G;
        constexpr int TPT = 256 / SPLIT;
        constexpr int BPS = NT / TPT;
        constexpr int CAP = 384, MAXROWS = 12;
        int*    cs   = (int*)smem;                        // 513 ints -> 2052 B
        float4* spts = (float4*)(smem + 2064);            // 384 x 16 B = 6144
        int*    meta = (int*)(smem + 2064 + CAP * 16);    // 34 ints
        int* bmn = meta;          // [3] (later: expanded box min)
        int* bmx = meta + 3;      // [3] (later: expanded box max)
        int* rowSeg = meta + 6;   // [12] global segment start (point idx)
        int* rowOff = meta + 18;  // [13] LDS prefix offsets
        int* mNR  = meta + 31;
        int* mTOT = meta + 32;
        int* mUSE = meta + 33;

        const int vb = blockIdx.x - 512;
        const int tLoc = tid >> 3;
        const int spl  = tid & (SPLIT - 1);
        const int smp = vb / BPS;
        const int blk = vb % BPS;
        const float4* sp = ptsG + (long)smp * NS;
        for (int i = tid; i < G3 + 1; i += 256) cs[i] = cstG[smp * (G3 + 1) + i];
        if (tid == 0) {
            bmn[0] = G; bmn[1] = G; bmn[2] = G;
            bmx[0] = -1; bmx[1] = -1; bmx[2] = -1;
        }
        __syncthreads();

        float4 q = ptsT[(long)smp * NT + blk * TPT + tLoc];
        float px = q.x, py = q.y, pz = q.z;
        const int jloc = __float_as_int(q.w);
        int cx = min(G - 1, max(0, (int)(px * (float)G)));
        int cy = min(G - 1, max(0, (int)(py * (float)G)));
        int cz = min(G - 1, max(0, (int)(pz * (float)G)));
        atomicMin(&bmn[0], cx); atomicMax(&bmx[0], cx);
        atomicMin(&bmn[1], cy); atomicMax(&bmx[1], cy);
        atomicMin(&bmn[2], cz); atomicMax(&bmx[2], cz);
        __syncthreads();
        if (tid == 0) {
            int x0 = max(bmn[0] - 1, 0), x1 = min(bmx[0] + 1, G - 1);
            int y0 = max(bmn[1] - 1, 0), y1 = min(bmx[1] + 1, G - 1);
            int z0 = max(bmn[2] - 1, 0), z1 = min(bmx[2] + 1, G - 1);
            int nr = (y1 - y0 + 1) * (z1 - z0 + 1);
            int tot = 0, ok = (nr <= MAXROWS);
            if (ok) {
                int r = 0;
                for (int Z = z0; Z <= z1; Z++)
                    for (int Y = y0; Y <= y1; Y++) {
                        int cb = (Z * G + Y) * G;
                        int s0 = cs[cb + x0], e0 = cs[cb + x1 + 1];
                        rowSeg[r] = s0; rowOff[r] = tot; tot += e0 - s0; r++;
                    }
                rowOff[nr] = tot;
                ok = (tot <= CAP);
            }
            mNR[0] = ok ? nr : 0; mTOT[0] = tot; mUSE[0] = ok;
            bmn[0] = x0; bmx[0] = x1;
            bmn[1] = y0; bmx[1] = y1;
            bmn[2] = z0; bmx[2] = z1;
        }
        __syncthreads();
        const int useStage = mUSE[0];

        float d0 = 1e30f, d1 = 1e30f, d2 = 1e30f;
        int i0 = 0x7FFFFFFF, i1 = 0x7FFFFFFF, i2 = 0x7FFFFFFF;

        auto insert = [&](float d, int j) {
            bool l0 = (d < d0) || (d == d0 && j < i0);
            bool l1 = (d < d1) || (d == d1 && j < i1);
            bool l2 = (d < d2) || (d == d2 && j < i2);
            float nd2 = l1 ? d1 : (l2 ? d : d2);
            int   ni2 = l1 ? i1 : (l2 ? j : i2);
            float nd1 = l0 ? d0 : (l1 ? d : d1);
            int   ni1 = l0 ? i0 : (l1 ? j : i1);
            d2 = nd2; i2 = ni2; d1 = nd1; i1 = ni1;
            d0 = l0 ? d : d0; i0 = l0 ? j : i0;
        };
        auto scanCell = [&](int cell) {     // global-memory scan (fallback + rings)
            int s = cs[cell], e = cs[cell + 1];
            for (int t = s + spl; t < e; t += SPLIT) {
                float4 c = sp[t];
                int j = __float_as_int(c.w);
                float dx = px - c.x, dy = py - c.y, dz = pz - c.z;
                float d = ((dx * dx) + (dy * dy)) + (dz * dz);
                insert(d, j);
            }
        };
        auto merge8 = [&]() {
            #pragma unroll
            for (int m = 1; m < SPLIT; m <<= 1) {
                float pd0 = __shfl_xor(d0, m), pd1 = __shfl_xor(d1, m), pd2 = __shfl_xor(d2, m);
                int   pi0 = __shfl_xor(i0, m), pi1 = __shfl_xor(i1, m), pi2 = __shfl_xor(i2, m);
                if (pi0 != i0 && pi0 != i1 && pi0 != i2) insert(pd0, pi0);
                if (pi1 != i0 && pi1 != i1 && pi1 != i2) insert(pd1, pi1);
                if (pi2 != i0 && pi2 != i1 && pi2 != i2) insert(pd2, pi2);
            }
        };

        if (useStage) {
            // cooperative stage of the block's box (contiguous per-(Z,Y) rows)
            const int nr = mNR[0];
            for (int r = 0; r < nr; r++) {
                int base0 = rowOff[r], len = rowOff[r + 1] - base0;
                for (int i = tid; i < len; i += 256) spts[base0 + i] = sp[rowSeg[r] + i];
            }
            __syncthreads();
            const int tot = mTOT[0];
            for (int t = spl; t < tot; t += SPLIT) {
                float4 c = spts[t];
                int j = __float_as_int(c.w);
                float dx = px - c.x, dy = py - c.y, dz = pz - c.z;
                float d = ((dx * dx) + (dy * dy)) + (dz * dz);
                insert(d, j);
            }
        } else {
            // fallback: original per-target 27-cell global scan
            #pragma unroll 1
            for (int o = 0; o < 27; o++) {
                int ox = o % 3 - 1, oy = (o / 3) % 3 - 1, oz = o / 9 - 1;
                int X = cx + ox, Y = cy + oy, Z = cz + oz;
                if (X < 0 || X >= G || Y < 0 || Y >= G || Z < 0 || Z >= G) continue;
                scanCell((Z * G + Y) * G + X);
            }
        }
        merge8();

        // rings s >= 2: skip box cells when staged (already scanned)
        #pragma unroll 1
        for (int s = 2; s < G; s++) {
            float rm = ((float)(s - 1) * h);
            float ringMin = rm * rm * 0.9999f;
            if (d2 < ringMin) break;
            #pragma unroll 1
            for (int oz = -s; oz <= s; oz++) {
                int Z = cz + oz; if (Z < 0 || Z >= G) continue;
                int az = oz < 0 ? -oz : oz;
                #pragma unroll 1
                for (int oy = -s; oy <= s; oy++) {
                    int Y = cy + oy; if (Y < 0 || Y >= G) continue;
                    int ay = oy < 0 ? -oy : oy;
                    bool outer = (az == s) || (ay == s);
                    #pragma unroll 1
                    for (int ox = -s; ox <= s; ox++) {
                        int ax = ox < 0 ? -ox : ox;
                        if (!outer && ax != s) continue;
                        int X = cx + ox; if (X < 0 || X >= G) continue;
                        if (useStage &&
                            X >= bmn[0] && X <= bmx[0] &&
                            Y >= bmn[1] && Y <= bmx[1] &&
                            Z >= bmn[2] && Z <= bmx[2]) continue;  // staged already
                        float lx = (float)X * h, ly = (float)Y * h, lz = (float)Z * h;
                        float ex = fmaxf(0.f, fmaxf(lx - px, px - (lx + h)));
                        float ey = fmaxf(0.f, fmaxf(ly - py, py - (ly + h)));
                        float ez = fmaxf(0.f, fmaxf(lz - pz, pz - (lz + h)));
                        float md = ((ex * ex) + (ey * ey)) + (ez * ez);
                        if (md * 0.9999f > d2) continue;
                        scanCell((Z * G + Y) * G + X);
                    }
                }
            }
            merge8();
        }

        if (spl == 0) {
            float wa = 1.f / fmaxf(d0, 1e-16f);
            float wb = 1.f / fmaxf(d1, 1e-16f);
            float wc = 1.f / fmaxf(d2, 1e-16f);
            float sw = wa + wb + wc;
            long tg = (long)smp * NT + jloc;
            i0d[tg * 3 + 0] = smp * NS + i0;
            i0d[tg * 3 + 1] = smp * NS + i1;
            i0d[tg * 3 + 2] = smp * NS + i2;
            w0d[tg * 3 + 0] = wa / sw;
            w0d[tg * 3 + 1] = wb / sw;
            w0d[tg * 3 + 2] = wc / sw;
        }
    }
}

// ===========================================================================
// PHASE 3: fused layer-2 MLP, 16-row slabs + WTf (round-10 proven).
// ===========================================================================
__global__ __launch_bounds__(256) void fpno_p3(
    const unsigned short* __restrict__ X1, const void* __restrict__ xs0,
    const unsigned short* __restrict__ WTf,
    const void* __restrict__ b1a, const void* __restrict__ b1b,
    const float* __restrict__ g1,
    const int* __restrict__ i0d, const float* __restrict__ w0d,
    const int* __restrict__ flagp,
    float* __restrict__ out) {
    #pragma clang fp contract(off)
    constexpr int LDX = 200;   // 192 + 8 pad (halves)
    constexpr int LDH = 136;   // 128 + 8 pad
    __shared__ __align__(16) char smem[10752];
    const int f32 = *flagp;
    const int tid = threadIdx.x;
    unsigned short* XC = (unsigned short*)smem;           // 6400 B
    unsigned short* Hs = (unsigned short*)(smem + 6400);  // 4352 B
    const int bm = blockIdx.x;

    for (int u = tid; u < 384; u += 256) {
        int row = u / 24, c0 = (u % 24) * 8;
        int gr = bm * 16 + row;
        unsigned short o[8];
        if (c0 < kC1) {
            int j0 = i0d[gr * 3 + 0], j1 = i0d[gr * 3 + 1], j2 = i0d[gr * 3 + 2];
            float ww0 = w0d[gr * 3 + 0], ww1 = w0d[gr * 3 + 1], ww2 = w0d[gr * 3 + 2];
            float a0[8], a1[8], a2[8];
            ld8(X1, (long)j0 * kC1 + c0, 0, a0);
            ld8(X1, (long)j1 * kC1 + c0, 0, a1);
            ld8(X1, (long)j2 * kC1 + c0, 0, a2);
            #pragma unroll
            for (int j = 0; j < 8; j++)
                o[j] = f2bs(ww0 * a0[j] + ww1 * a1[j] + ww2 * a2[j]);
        } else {
            float s8[8];
            ld8(xs0, (long)gr * kC0 + (c0 - kC1), f32, s8);
            #pragma unroll
            for (int j = 0; j < 8; j++) o[j] = f2bs(s8[j]);
        }
        *(uint4*)&XC[row * LDX + c0] = pack8(o);
    }
    __syncthreads();

    const int lane = tid & 63, w = tid >> 6;
    const int l16 = lane & 15, quad = lane >> 4;
    v4f acc[2];
    #pragma unroll
    for (int t = 0; t < 2; t++) acc[t] = (v4f){0.f, 0.f, 0.f, 0.f};
    #pragma unroll 1
    for (int k0 = 0; k0 < 192; k0 += 32) {
        const v8s a = *(const v8s*)&XC[l16 * LDX + k0 + quad * 8];
        int kc = k0 >> 5;
        #pragma unroll
        for (int t = 0; t < 2; t++) {
            int tg = w * 2 + t;                 // col-tile 0..7 (N=128)
            const v8s bfr = *(const v8s*)&WTf[131072 + (((kc * 8 + tg) << 6) + lane) * 8];
            acc[t] = __builtin_amdgcn_mfma_f32_16x16x32_bf16(a, bfr, acc[t], 0, 0, 0);
        }
    }
    #pragma unroll
    for (int t = 0; t < 2; t++) {
        int c = (w * 2 + t) * 16 + l16;
        float bb = rdIn(b1a, c, f32);
        #pragma unroll
        for (int i = 0; i < 4; i++)
            Hs[(quad * 4 + i) * LDH + c] = f2bs(tanhf(acc[t][i] + bb));
    }
    __syncthreads();

    v4f acc2 = (v4f){0.f, 0.f, 0.f, 0.f};
    #pragma unroll 1
    for (int k0 = 0; k0 < 128; k0 += 32) {
        const v8s a = *(const v8s*)&Hs[l16 * LDH + k0 + quad * 8];
        int kc = k0 >> 5;
        const v8s bfr = *(const v8s*)&WTf[155648 + (((kc * 4 + w) << 6) + lane) * 8];
        acc2 = __builtin_amdgcn_mfma_f32_16x16x32_bf16(a, bfr, acc2, 0, 0, 0);
    }
    {
        int c = w * 16 + l16;
        float bb = rdIn(b1b, c, f32);
        #pragma unroll
        for (int i = 0; i < 4; i++) {
            int gr = bm * 16 + quad * 4 + i;
            float v = (acc2[i] + bb) * g1[(gr >> 13) * 64 + c];
            out[(long)gr * 64 + c] = v;
        }
    }
}

// ===========================================================================
extern "C" void kernel_launch(void* const* d_in, const int* in_sizes, int n_in,
                              void* d_out, int out_size, void* d_ws, size_t ws_size,
                              hipStream_t stream) {
    (void)out_size;
    float* out = (float*)d_out;   // fp32 output buffer
    const int R1 = kB * kN1;  // 8192
    const int R0 = kB * kN0;  // 32768

    static const int kExp[22] = {
        256, 524288, 6144, 2048, 1048576, 24576, 8192, 2097152, 98304, 32768,
        98304, 256, 32768, 128, 8192, 128, 24576, 128, 8192, 64, 4096, 64};
    if (n_in != 22) { fpno_guard<<<1, 64, 0, stream>>>(3072.0f, out); return; }
    for (int i = 0; i < 22; i++) {
        if (in_sizes[i] != kExp[i]) {
            fpno_guard<<<1, 64, 0, stream>>>(1024.0f + 8.0f * i, out);
            return;
        }
    }

    // ---- workspace (~3.6 MB) ----
    char* base = (char*)d_ws;
    size_t off = 0;
    auto alloc = [&](size_t bytes) {
        off = (off + 255) & ~(size_t)255; size_t o = off; off += bytes; return o;
    };
    int*            flag = (int*)(base + alloc(4));
    float*          g0   = (float*)(base + alloc(kB * 128 * 4));
    float*          g1   = (float*)(base + alloc(kB * 64 * 4));
    int*            i1d  = (int*)(base + alloc((size_t)R1 * 3 * 4));
    float*          w1d  = (float*)(base + alloc((size_t)R1 * 3 * 4));
    int*            i0d  = (int*)(base + alloc((size_t)R0 * 3 * 4));
    float*          w0d  = (float*)(base + alloc((size_t)R0 * 3 * 4));
    float4*         ptsG = (float4*)(base + alloc((size_t)kB * kN1 * 16));        // 128 KB
    int*            cstG = (int*)(base + alloc((size_t)kB * (512 + 1) * 4));
    float4*         ptsT = (float4*)(base + alloc((size_t)kB * kN0 * 16));        // 512 KB
    int*            cstT = (int*)(base + alloc((size_t)kB * (512 + 1) * 4));
    unsigned short* WT   = (unsigned short*)(base + alloc(163840 * 2));           // 320 KB
    unsigned short* X1   = (unsigned short*)(base + alloc((size_t)R1 * 128 * 2)); // 2 MB
    if (ws_size < off) { fpno_guard<<<1, 64, 0, stream>>>(2048.0f, out); return; }

    const void* par  = d_in[0];
    const void* x    = d_in[1];
    const void* pos  = d_in[2];
    const void* xs1  = d_in[4];
    const void* pos1 = d_in[5];
    const void* xs0  = d_in[7];
    const void* pos0 = d_in[8];
    const int*  bt0  = (const int*)d_in[9];
    const void *W0a = d_in[10], *b0a = d_in[11], *W0b = d_in[12], *b0b = d_in[13];
    const void *Wp0 = d_in[14], *bp0 = d_in[15];
    const void *W1a = d_in[16], *b1a = d_in[17], *W1b = d_in[18], *b1b = d_in[19];
    const void *Wp1 = d_in[20], *bp1 = d_in[21];

    // PHASE 1: wconv(frag-order) | gates | layer-1 kNN | bins | tail
    fpno_p1<<<714, 512, 0, stream>>>(
        (const unsigned int*)pos, pos, pos1, pos0,
        W0a, W0b, W1a, W1b, par, Wp0, bp0, Wp1, bp1, bt0,
        flag, WT, g0, g1, i1d, w1d, ptsG, cstG, ptsT, cstT, out);

    // PHASE 2: fused layer-1 MLP (512 blocks) | box-staged layer-2 kNN (1024)
    fpno_p2<<<1536, 256, 0, stream>>>(
        x, xs1, WT, b0a, b0b, g0, i1d, w1d,
        ptsG, cstG, ptsT, flag, X1, i0d, w0d);

    // PHASE 3: fused layer-2 MLP 16-row slabs -> fp32 out  (2048 blocks)
    fpno_p3<<<2048, 256, 0, stream>>>(
        X1, xs0, WT, b1a, b1b, g1, i0d, w0d, flag, out);
}

// Round 12
// 169.171 us; speedup vs baseline: 1.1328x; 1.1328x over previous
//
#include <hip/hip_runtime.h>
#include <hip/hip_bf16.h>

using bf16 = __hip_bfloat16;
using v8s = __attribute__((ext_vector_type(8))) short;   // MFMA A/B frag: 8 bf16
using v4f = __attribute__((ext_vector_type(4))) float;   // MFMA C/D frag

// Problem constants (from reference)
constexpr int kB = 4, kM = 64;
constexpr int kN2 = 512, kN1 = 2048, kN0 = 8192;
constexpr int kC2 = 256, kC1 = 128, kC0 = 64;

__device__ __forceinline__ float bs2f(unsigned short u) {
    return __uint_as_float((unsigned)u << 16);
}
__device__ __forceinline__ unsigned short f2bs(float f) {  // RNE fp32->bf16
    unsigned u = __float_as_uint(f);
    u += 0x7FFFu + ((u >> 16) & 1u);
    return (unsigned short)(u >> 16);
}
__device__ __forceinline__ float rdIn(const void* p, long i, int f32) {
    return f32 ? ((const float*)p)[i] : bs2f(((const unsigned short*)p)[i]);
}
__device__ __forceinline__ unsigned short rdBS(const void* p, long i, int f32) {
    return f32 ? f2bs(((const float*)p)[i]) : ((const unsigned short*)p)[i];
}
// load 8 consecutive elements as fp32 (16B-aligned offsets only)
__device__ __forceinline__ void ld8(const void* p, long off, int f32, float v[8]) {
    if (f32) {
        const float* fp = (const float*)p + off;
        float4 a = *(const float4*)fp;
        float4 b = *(const float4*)(fp + 4);
        v[0] = a.x; v[1] = a.y; v[2] = a.z; v[3] = a.w;
        v[4] = b.x; v[5] = b.y; v[6] = b.z; v[7] = b.w;
    } else {
        const unsigned short* hp = (const unsigned short*)p + off;
        uint4 u = *(const uint4*)hp;
        unsigned w[4] = {u.x, u.y, u.z, u.w};
        #pragma unroll
        for (int i = 0; i < 4; i++) {
            v[2 * i]     = bs2f((unsigned short)(w[i] & 0xFFFFu));
            v[2 * i + 1] = bs2f((unsigned short)(w[i] >> 16));
        }
    }
}
__device__ __forceinline__ uint4 pack8(const unsigned short o[8]) {
    uint4 u;
    u.x = (unsigned)o[0] | ((unsigned)o[1] << 16);
    u.y = (unsigned)o[2] | ((unsigned)o[3] << 16);
    u.z = (unsigned)o[4] | ((unsigned)o[5] << 16);
    u.w = (unsigned)o[6] | ((unsigned)o[7] << 16);
    return u;
}

__global__ void fpno_guard(float code, float* __restrict__ out) {
    if (threadIdx.x == 0) out[0] = code;
}

// ===========================================================================
// PHASE 1 (one launch, 512 thr): wconv(frag-order) | gates | layer-1 kNN |
// bin x2 | tail.  (round-10 proven)
// ===========================================================================
__global__ __launch_bounds__(512) void fpno_p1(
    const unsigned int* __restrict__ posW,
    const void* __restrict__ pos,
    const void* __restrict__ pos1,
    const void* __restrict__ pos0,
    const void* __restrict__ W0a, const void* __restrict__ W0b,
    const void* __restrict__ W1a, const void* __restrict__ W1b,
    const void* __restrict__ par,
    const void* __restrict__ Wp0, const void* __restrict__ bp0,
    const void* __restrict__ Wp1, const void* __restrict__ bp1,
    const int* __restrict__ bt0,
    int* __restrict__ flag, unsigned short* __restrict__ WT,
    float* __restrict__ g0, float* __restrict__ g1,
    int* __restrict__ i1d, float* __restrict__ w1d,
    float4* __restrict__ ptsG, int* __restrict__ cstG,
    float4* __restrict__ ptsT, int* __restrict__ cstT,
    float* __restrict__ out) {
    #pragma clang fp contract(off)
    __shared__ __align__(16) char smem[20480];
    __shared__ int sflg[2];
    const int b = blockIdx.x, tid = threadIdx.x;

    if (tid == 0) { sflg[0] = 0; sflg[1] = 0; }
    __syncthreads();
    {
        unsigned lo = posW[tid] & 0xFFFFu;   // words 0..511
        int bad = 0, nz = 0;
        if (lo != 0u) { nz = 1; if ((lo & 0x8000u) || lo > 0x3F80u) bad = 1; }
        if (bad) sflg[0] = 1;
        if (nz) sflg[1] = 1;
    }
    __syncthreads();
    const int f32 = (sflg[0] || !sflg[1]) ? 1 : 0;
    if (b == 0 && tid == 0) *flag = f32;

    if (b < 320) {
        // ---- weight convert to FRAGMENT-ordered bf16 (WTf) ----
        int id = b * 512 + tid;
        const void* src; int N; int base, local;
        if      (id < 98304)  { src = W0a; N = 256; base = 0;      local = id; }
        else if (id < 131072) { src = W0b; N = 128; base = 98304;  local = id - 98304; }
        else if (id < 155648) { src = W1a; N = 128; base = 131072; local = id - 131072; }
        else                  { src = W1b; N = 64;  base = 155648; local = id - 155648; }
        int NT = N >> 4;
        int e = local & 7;
        int l = (local >> 3) & 63;
        int rest = local >> 9;
        int t = rest % NT;
        int kc = rest / NT;
        int n = t * 16 + (l & 15);
        int k = kc * 32 + ((l >> 4) << 3) + e;
        WT[base + local] = rdBS(src, (long)k * N + n, f32);
    } else if (b < 322) {
        int id = (b - 320) * 512 + tid;
        if (id < kB * 128) {
            int bb = id / 128, n = id % 128;
            float a = rdIn(bp0, n, f32);
            for (int m = 0; m < kM; m++)
                a += rdIn(par, bb * kM + m, f32) * rdIn(Wp0, m * 128 + n, f32);
            g0[id] = tanhf(a);
        } else if (id < kB * 128 + kB * 64) {
            int id2 = id - kB * 128;
            int bb = id2 / 64, n = id2 % 64;
            float a = rdIn(bp1, n, f32);
            for (int m = 0; m < kM; m++)
                a += rdIn(par, bb * kM + m, f32) * rdIn(Wp1, m * 64 + n, f32);
            g1[id2] = tanhf(a);
        }
    } else if (b < 450) {
        constexpr int NS = kN2;
        float4* sp = (float4*)smem;
        float*  cd = (float*)(smem + 8192);
        int*    ci = (int*)(smem + 14336);
        const int blk = b - 322;
        const int tLoc = tid >> 3;
        const int spl  = tid & 7;
        const int tGlob = blk * 64 + tLoc;
        const int smp = tGlob / kN1;
        for (int i = tid; i < NS; i += 512) {
            long bb = (long)(smp * NS + i) * 3;
            sp[i] = make_float4(rdIn(pos, bb, f32), rdIn(pos, bb + 1, f32),
                                rdIn(pos, bb + 2, f32), 0.f);
        }
        __syncthreads();
        long tb = (long)tGlob * 3;
        float px = rdIn(pos1, tb, f32), py = rdIn(pos1, tb + 1, f32),
              pz = rdIn(pos1, tb + 2, f32);
        float d0 = 1e30f, d1 = 1e30f, d2 = 1e30f;
        int i0 = 0x7FFFFFFF, i1 = 0x7FFFFFFF, i2 = 0x7FFFFFFF;
        for (int j = spl; j < NS; j += 8) {
            float4 s = sp[j];
            float dx = px - s.x, dy = py - s.y, dz = pz - s.z;
            float d = ((dx * dx) + (dy * dy)) + (dz * dz);
            bool l0 = d < d0, l1 = d < d1, l2 = d < d2;
            float nd2 = l1 ? d1 : (l2 ? d : d2);
            int   ni2 = l1 ? i1 : (l2 ? j : i2);
            float nd1 = l0 ? d0 : (l1 ? d : d1);
            int   ni1 = l0 ? i0 : (l1 ? j : i1);
            float nd0 = l0 ? d : d0;
            int   ni0 = l0 ? j : i0;
            d2 = nd2; i2 = ni2; d1 = nd1; i1 = ni1; d0 = nd0; i0 = ni0;
        }
        cd[tid * 3 + 0] = d0; ci[tid * 3 + 0] = i0;
        cd[tid * 3 + 1] = d1; ci[tid * 3 + 1] = i1;
        cd[tid * 3 + 2] = d2; ci[tid * 3 + 2] = i2;
        __syncthreads();
        if (spl == 0) {
            float b0 = 1e30f, b1 = 1e30f, b2 = 1e30f;
            int k0 = 0x7FFFFFFF, k1 = 0x7FFFFFFF, k2 = 0x7FFFFFFF;
            int qb = tLoc * 24;
            for (int q = 0; q < 24; q++) {
                float d = cd[qb + q];
                int i = ci[qb + q];
                if ((d < b2) || (d == b2 && i < k2)) {
                    if ((d < b1) || (d == b1 && i < k1)) {
                        b2 = b1; k2 = k1;
                        if ((d < b0) || (d == b0 && i < k0)) { b1 = b0; k1 = k0; b0 = d; k0 = i; }
                        else                                  { b1 = d;  k1 = i; }
                    } else { b2 = d; k2 = i; }
                }
            }
            float wa = 1.f / fmaxf(b0, 1e-16f);
            float wb = 1.f / fmaxf(b1, 1e-16f);
            float wc = 1.f / fmaxf(b2, 1e-16f);
            float s = wa + wb + wc;
            i1d[tGlob * 3 + 0] = smp * NS + k0;
            i1d[tGlob * 3 + 1] = smp * NS + k1;
            i1d[tGlob * 3 + 2] = smp * NS + k2;
            w1d[tGlob * 3 + 0] = wa / s;
            w1d[tGlob * 3 + 1] = wb / s;
            w1d[tGlob * 3 + 2] = wc / s;
        }
    } else if (b < 458) {
        constexpr int G3 = 512;
        int* cnt = (int*)smem;
        int* sc  = cnt + G3;
        int* cur = sc + G3;
        const bool srcSide = (b < 454);
        const int smp = srcSide ? (b - 450) : (b - 454);
        const int NSb = srcSide ? kN1 : kN0;
        const int PPT = NSb / 512;
        const void* P = srcSide ? pos1 : pos0;
        float4* pts = srcSide ? ptsG : ptsT;
        int* cstart = srcSide ? cstG : cstT;
        for (int i = tid; i < G3; i += 512) cnt[i] = 0;
        __syncthreads();
        float4 p[16]; int cl[16];
        for (int r = 0; r < PPT; r++) {
            int j = r * 512 + tid;
            long bb = ((long)smp * NSb + j) * 3;
            float x = rdIn(P, bb, f32), y = rdIn(P, bb + 1, f32), z = rdIn(P, bb + 2, f32);
            int cx = min(7, max(0, (int)(x * 8.f)));
            int cy = min(7, max(0, (int)(y * 8.f)));
            int cz = min(7, max(0, (int)(z * 8.f)));
            cl[r] = (cz * 8 + cy) * 8 + cx;
            p[r] = make_float4(x, y, z, __int_as_float(j));
            atomicAdd(&cnt[cl[r]], 1);
        }
        __syncthreads();
        int v = cnt[tid];
        sc[tid] = v;
        __syncthreads();
        for (int ofs = 1; ofs < G3; ofs <<= 1) {
            int t = 0;
            if (tid >= ofs) t = sc[tid - ofs];
            __syncthreads();
            sc[tid] += t;
            __syncthreads();
        }
        {
            int st = sc[tid] - v;
            cur[tid] = st;
            cstart[smp * (G3 + 1) + tid] = st;
        }
        if (tid == 0) cstart[smp * (G3 + 1) + G3] = NSb;
        __syncthreads();
        for (int r = 0; r < PPT; r++) {
            int slot = atomicAdd(&cur[cl[r]], 1);
            pts[(long)smp * NSb + slot] = p[r];
        }
    } else {
        int id = (b - 458) * 512 + tid;
        const int nX = kB * kN0 * kC0;
        const int nP = kB * kN0 * 3;
        if (id < nP) out[nX + id] = rdIn(pos0, id, f32);
        else         out[nX + id] = (float)bt0[id - nP];
    }
}

// ===========================================================================
// PHASE 2 (one launch, 256 thr), co-scheduled (round-10 proven):
//   blocks [0,512):     fused layer-1 MLP, 16-row slabs + WTf.
//   blocks [512,1536):  layer-2 grid kNN (direct-global pts, 2KB LDS,
//                       shuffle-merge). Round-11 box-staging REVERTED:
//                       union-superset doubled per-lane work (box spans
//                       2-4 home cells along x) + 4x LDS bank conflicts.
// ===========================================================================
__global__ __launch_bounds__(256) void fpno_p2(
    const void* __restrict__ x, const void* __restrict__ xs1,
    const unsigned short* __restrict__ WTf,
    const void* __restrict__ b0a, const void* __restrict__ b0b,
    const float* __restrict__ g0,
    const int* __restrict__ i1d, const float* __restrict__ w1d,
    const float4* __restrict__ ptsG, const int* __restrict__ cstG,
    const float4* __restrict__ ptsT,
    const int* __restrict__ flagp,
    unsigned short* __restrict__ X1,
    int* __restrict__ i0d, float* __restrict__ w0d) {
    #pragma clang fp contract(off)
    __shared__ __align__(16) char smem[21504];
    const int tid = threadIdx.x;

    if (blockIdx.x < 512) {
        // ================= fused layer-1 MLP, 16-row slab =================
        constexpr int LDX = 392;   // 384 + 8 pad (halves)
        constexpr int LDH = 264;   // 256 + 8 pad
        const int f32 = *flagp;
        unsigned short* XC = (unsigned short*)smem;            // 12544 B
        unsigned short* Hs = (unsigned short*)(smem + 12544);  // 8448 B
        const int bm = blockIdx.x;

        for (int u = tid; u < 768; u += 256) {
            int row = u / 48, c0 = (u % 48) * 8;
            int gr = bm * 16 + row;
            unsigned short o[8];
            if (c0 < kC2) {
                int j0 = i1d[gr * 3 + 0], j1 = i1d[gr * 3 + 1], j2 = i1d[gr * 3 + 2];
                float ww0 = w1d[gr * 3 + 0], ww1 = w1d[gr * 3 + 1], ww2 = w1d[gr * 3 + 2];
                float a0[8], a1[8], a2[8];
                ld8(x, (long)j0 * kC2 + c0, f32, a0);
                ld8(x, (long)j1 * kC2 + c0, f32, a1);
                ld8(x, (long)j2 * kC2 + c0, f32, a2);
                #pragma unroll
                for (int j = 0; j < 8; j++)
                    o[j] = f2bs(ww0 * a0[j] + ww1 * a1[j] + ww2 * a2[j]);
            } else {
                float s8[8];
                ld8(xs1, (long)gr * kC1 + (c0 - kC2), f32, s8);
                #pragma unroll
                for (int j = 0; j < 8; j++) o[j] = f2bs(s8[j]);
            }
            *(uint4*)&XC[row * LDX + c0] = pack8(o);
        }
        __syncthreads();

        const int lane = tid & 63, w = tid >> 6;
        const int l16 = lane & 15, quad = lane >> 4;
        v4f acc[4];
        #pragma unroll
        for (int t = 0; t < 4; t++) acc[t] = (v4f){0.f, 0.f, 0.f, 0.f};
        #pragma unroll 1
        for (int k0 = 0; k0 < 384; k0 += 32) {
            const v8s a = *(const v8s*)&XC[l16 * LDX + k0 + quad * 8];
            int kc = k0 >> 5;
            #pragma unroll
            for (int t = 0; t < 4; t++) {
                int tg = w * 4 + t;                 // col-tile 0..15 (N=256)
                const v8s bfr = *(const v8s*)&WTf[(((kc * 16 + tg) << 6) + lane) * 8];
                acc[t] = __builtin_amdgcn_mfma_f32_16x16x32_bf16(a, bfr, acc[t], 0, 0, 0);
            }
        }
        #pragma unroll
        for (int t = 0; t < 4; t++) {
            int c = (w * 4 + t) * 16 + l16;
            float bb = rdIn(b0a, c, f32);
            #pragma unroll
            for (int i = 0; i < 4; i++)
                Hs[(quad * 4 + i) * LDH + c] = f2bs(tanhf(acc[t][i] + bb));
        }
        __syncthreads();

        v4f acc2[2];
        #pragma unroll
        for (int t = 0; t < 2; t++) acc2[t] = (v4f){0.f, 0.f, 0.f, 0.f};
        #pragma unroll 1
        for (int k0 = 0; k0 < 256; k0 += 32) {
            const v8s a = *(const v8s*)&Hs[l16 * LDH + k0 + quad * 8];
            int kc = k0 >> 5;
            #pragma unroll
            for (int t = 0; t < 2; t++) {
                int tg = w * 2 + t;                 // col-tile 0..7 (N=128)
                const v8s bfr = *(const v8s*)&WTf[98304 + (((kc * 8 + tg) << 6) + lane) * 8];
                acc2[t] = __builtin_amdgcn_mfma_f32_16x16x32_bf16(a, bfr, acc2[t], 0, 0, 0);
            }
        }
        #pragma unroll
        for (int t = 0; t < 2; t++) {
            int c = (w * 2 + t) * 16 + l16;
            float bb = rdIn(b0b, c, f32);
            #pragma unroll
            for (int i = 0; i < 4; i++) {
                int gr = bm * 16 + quad * 4 + i;
                float v = tanhf(acc2[t][i] + bb) * g0[(gr >> 11) * 128 + c];
                X1[(long)gr * 128 + c] = f2bs(v);
            }
        }
    } else {
        // ================= layer-2 grid kNN (round-10 proven) =================
        constexpr int NS = kN1, NT = kN0, G = 8, SPLIT = 8;
        constexpr int G3 = G * G * G;
        constexpr float h = 1.0f / (float)G;
        constexpr int TPT = 256 / SPLIT;
        constexpr int BPS = NT / TPT;
        int* cs = (int*)smem;                      // 2052 B
        const int vb = blockIdx.x - 512;
        const int tLoc = tid >> 3;
        const int spl  = tid & (SPLIT - 1);
        const int smp = vb / BPS;
        const int blk = vb % BPS;
        const float4* sp = ptsG + (long)smp * NS;  // L1/L2-resident candidates
        for (int i = tid; i < G3 + 1; i += 256) cs[i] = cstG[smp * (G3 + 1) + i];
        __syncthreads();

        float4 q = ptsT[(long)smp * NT + blk * TPT + tLoc];
        float px = q.x, py = q.y, pz = q.z;
        const int jloc = __float_as_int(q.w);
        int cx = min(G - 1, max(0, (int)(px * (float)G)));
        int cy = min(G - 1, max(0, (int)(py * (float)G)));
        int cz = min(G - 1, max(0, (int)(pz * (float)G)));
        float d0 = 1e30f, d1 = 1e30f, d2 = 1e30f;
        int i0 = 0x7FFFFFFF, i1 = 0x7FFFFFFF, i2 = 0x7FFFFFFF;

        auto insert = [&](float d, int j) {
            bool l0 = (d < d0) || (d == d0 && j < i0);
            bool l1 = (d < d1) || (d == d1 && j < i1);
            bool l2 = (d < d2) || (d == d2 && j < i2);
            float nd2 = l1 ? d1 : (l2 ? d : d2);
            int   ni2 = l1 ? i1 : (l2 ? j : i2);
            float nd1 = l0 ? d0 : (l1 ? d : d1);
            int   ni1 = l0 ? i0 : (l1 ? j : i1);
            d2 = nd2; i2 = ni2; d1 = nd1; i1 = ni1;
            d0 = l0 ? d : d0; i0 = l0 ? j : i0;
        };
        auto scanCell = [&](int cell) {
            int s = cs[cell], e = cs[cell + 1];
            for (int t = s + spl; t < e; t += SPLIT) {
                float4 c = sp[t];
                int j = __float_as_int(c.w);
                float dx = px - c.x, dy = py - c.y, dz = pz - c.z;
                float d = ((dx * dx) + (dy * dy)) + (dz * dz);
                insert(d, j);
            }
        };
        auto merge8 = [&]() {
            #pragma unroll
            for (int m = 1; m < SPLIT; m <<= 1) {
                float pd0 = __shfl_xor(d0, m), pd1 = __shfl_xor(d1, m), pd2 = __shfl_xor(d2, m);
                int   pi0 = __shfl_xor(i0, m), pi1 = __shfl_xor(i1, m), pi2 = __shfl_xor(i2, m);
                if (pi0 != i0 && pi0 != i1 && pi0 != i2) insert(pd0, pi0);
                if (pi1 != i0 && pi1 != i1 && pi1 != i2) insert(pd1, pi1);
                if (pi2 != i0 && pi2 != i1 && pi2 != i2) insert(pd2, pi2);
            }
        };

        #pragma unroll 1
        for (int o = 0; o < 27; o++) {
            int ox = o % 3 - 1, oy = (o / 3) % 3 - 1, oz = o / 9 - 1;
            int X = cx + ox, Y = cy + oy, Z = cz + oz;
            if (X < 0 || X >= G || Y < 0 || Y >= G || Z < 0 || Z >= G) continue;
            scanCell((Z * G + Y) * G + X);
        }
        merge8();

        #pragma unroll 1
        for (int s = 2; s < G; s++) {
            float rm = ((float)(s - 1) * h);
            float ringMin = rm * rm * 0.9999f;
            if (d2 < ringMin) break;
            #pragma unroll 1
            for (int oz = -s; oz <= s; oz++) {
                int Z = cz + oz; if (Z < 0 || Z >= G) continue;
                int az = oz < 0 ? -oz : oz;
                #pragma unroll 1
                for (int oy = -s; oy <= s; oy++) {
                    int Y = cy + oy; if (Y < 0 || Y >= G) continue;
                    int ay = oy < 0 ? -oy : oy;
                    bool outer = (az == s) || (ay == s);
                    #pragma unroll 1
                    for (int ox = -s; ox <= s; ox++) {
                        int ax = ox < 0 ? -ox : ox;
                        if (!outer && ax != s) continue;
                        int X = cx + ox; if (X < 0 || X >= G) continue;
                        float lx = (float)X * h, ly = (float)Y * h, lz = (float)Z * h;
                        float ex = fmaxf(0.f, fmaxf(lx - px, px - (lx + h)));
                        float ey = fmaxf(0.f, fmaxf(ly - py, py - (ly + h)));
                        float ez = fmaxf(0.f, fmaxf(lz - pz, pz - (lz + h)));
                        float md = ((ex * ex) + (ey * ey)) + (ez * ez);
                        if (md * 0.9999f > d2) continue;
                        scanCell((Z * G + Y) * G + X);
                    }
                }
            }
            merge8();
        }

        if (spl == 0) {
            float wa = 1.f / fmaxf(d0, 1e-16f);
            float wb = 1.f / fmaxf(d1, 1e-16f);
            float wc = 1.f / fmaxf(d2, 1e-16f);
            float sw = wa + wb + wc;
            long tg = (long)smp * NT + jloc;
            i0d[tg * 3 + 0] = smp * NS + i0;
            i0d[tg * 3 + 1] = smp * NS + i1;
            i0d[tg * 3 + 2] = smp * NS + i2;
            w0d[tg * 3 + 0] = wa / sw;
            w0d[tg * 3 + 1] = wb / sw;
            w0d[tg * 3 + 2] = wc / sw;
        }
    }
}

// ===========================================================================
// PHASE 3: fused layer-2 MLP, 16-row slabs + WTf (round-10 proven).
// ===========================================================================
__global__ __launch_bounds__(256) void fpno_p3(
    const unsigned short* __restrict__ X1, const void* __restrict__ xs0,
    const unsigned short* __restrict__ WTf,
    const void* __restrict__ b1a, const void* __restrict__ b1b,
    const float* __restrict__ g1,
    const int* __restrict__ i0d, const float* __restrict__ w0d,
    const int* __restrict__ flagp,
    float* __restrict__ out) {
    #pragma clang fp contract(off)
    constexpr int LDX = 200;   // 192 + 8 pad (halves)
    constexpr int LDH = 136;   // 128 + 8 pad
    __shared__ __align__(16) char smem[10752];
    const int f32 = *flagp;
    const int tid = threadIdx.x;
    unsigned short* XC = (unsigned short*)smem;           // 6400 B
    unsigned short* Hs = (unsigned short*)(smem + 6400);  // 4352 B
    const int bm = blockIdx.x;

    for (int u = tid; u < 384; u += 256) {
        int row = u / 24, c0 = (u % 24) * 8;
        int gr = bm * 16 + row;
        unsigned short o[8];
        if (c0 < kC1) {
            int j0 = i0d[gr * 3 + 0], j1 = i0d[gr * 3 + 1], j2 = i0d[gr * 3 + 2];
            float ww0 = w0d[gr * 3 + 0], ww1 = w0d[gr * 3 + 1], ww2 = w0d[gr * 3 + 2];
            float a0[8], a1[8], a2[8];
            ld8(X1, (long)j0 * kC1 + c0, 0, a0);
            ld8(X1, (long)j1 * kC1 + c0, 0, a1);
            ld8(X1, (long)j2 * kC1 + c0, 0, a2);
            #pragma unroll
            for (int j = 0; j < 8; j++)
                o[j] = f2bs(ww0 * a0[j] + ww1 * a1[j] + ww2 * a2[j]);
        } else {
            float s8[8];
            ld8(xs0, (long)gr * kC0 + (c0 - kC1), f32, s8);
            #pragma unroll
            for (int j = 0; j < 8; j++) o[j] = f2bs(s8[j]);
        }
        *(uint4*)&XC[row * LDX + c0] = pack8(o);
    }
    __syncthreads();

    const int lane = tid & 63, w = tid >> 6;
    const int l16 = lane & 15, quad = lane >> 4;
    v4f acc[2];
    #pragma unroll
    for (int t = 0; t < 2; t++) acc[t] = (v4f){0.f, 0.f, 0.f, 0.f};
    #pragma unroll 1
    for (int k0 = 0; k0 < 192; k0 += 32) {
        const v8s a = *(const v8s*)&XC[l16 * LDX + k0 + quad * 8];
        int kc = k0 >> 5;
        #pragma unroll
        for (int t = 0; t < 2; t++) {
            int tg = w * 2 + t;                 // col-tile 0..7 (N=128)
            const v8s bfr = *(const v8s*)&WTf[131072 + (((kc * 8 + tg) << 6) + lane) * 8];
            acc[t] = __builtin_amdgcn_mfma_f32_16x16x32_bf16(a, bfr, acc[t], 0, 0, 0);
        }
    }
    #pragma unroll
    for (int t = 0; t < 2; t++) {
        int c = (w * 2 + t) * 16 + l16;
        float bb = rdIn(b1a, c, f32);
        #pragma unroll
        for (int i = 0; i < 4; i++)
            Hs[(quad * 4 + i) * LDH + c] = f2bs(tanhf(acc[t][i] + bb));
    }
    __syncthreads();

    v4f acc2 = (v4f){0.f, 0.f, 0.f, 0.f};
    #pragma unroll 1
    for (int k0 = 0; k0 < 128; k0 += 32) {
        const v8s a = *(const v8s*)&Hs[l16 * LDH + k0 + quad * 8];
        int kc = k0 >> 5;
        const v8s bfr = *(const v8s*)&WTf[155648 + (((kc * 4 + w) << 6) + lane) * 8];
        acc2 = __builtin_amdgcn_mfma_f32_16x16x32_bf16(a, bfr, acc2, 0, 0, 0);
    }
    {
        int c = w * 16 + l16;
        float bb = rdIn(b1b, c, f32);
        #pragma unroll
        for (int i = 0; i < 4; i++) {
            int gr = bm * 16 + quad * 4 + i;
            float v = (acc2[i] + bb) * g1[(gr >> 13) * 64 + c];
            out[(long)gr * 64 + c] = v;
        }
    }
}

// ===========================================================================
extern "C" void kernel_launch(void* const* d_in, const int* in_sizes, int n_in,
                              void* d_out, int out_size, void* d_ws, size_t ws_size,
                              hipStream_t stream) {
    (void)out_size;
    float* out = (float*)d_out;   // fp32 output buffer
    const int R1 = kB * kN1;  // 8192
    const int R0 = kB * kN0;  // 32768

    static const int kExp[22] = {
        256, 524288, 6144, 2048, 1048576, 24576, 8192, 2097152, 98304, 32768,
        98304, 256, 32768, 128, 8192, 128, 24576, 128, 8192, 64, 4096, 64};
    if (n_in != 22) { fpno_guard<<<1, 64, 0, stream>>>(3072.0f, out); return; }
    for (int i = 0; i < 22; i++) {
        if (in_sizes[i] != kExp[i]) {
            fpno_guard<<<1, 64, 0, stream>>>(1024.0f + 8.0f * i, out);
            return;
        }
    }

    // ---- workspace (~3.6 MB) ----
    char* base = (char*)d_ws;
    size_t off = 0;
    auto alloc = [&](size_t bytes) {
        off = (off + 255) & ~(size_t)255; size_t o = off; off += bytes; return o;
    };
    int*            flag = (int*)(base + alloc(4));
    float*          g0   = (float*)(base + alloc(kB * 128 * 4));
    float*          g1   = (float*)(base + alloc(kB * 64 * 4));
    int*            i1d  = (int*)(base + alloc((size_t)R1 * 3 * 4));
    float*          w1d  = (float*)(base + alloc((size_t)R1 * 3 * 4));
    int*            i0d  = (int*)(base + alloc((size_t)R0 * 3 * 4));
    float*          w0d  = (float*)(base + alloc((size_t)R0 * 3 * 4));
    float4*         ptsG = (float4*)(base + alloc((size_t)kB * kN1 * 16));        // 128 KB
    int*            cstG = (int*)(base + alloc((size_t)kB * (512 + 1) * 4));
    float4*         ptsT = (float4*)(base + alloc((size_t)kB * kN0 * 16));        // 512 KB
    int*            cstT = (int*)(base + alloc((size_t)kB * (512 + 1) * 4));
    unsigned short* WT   = (unsigned short*)(base + alloc(163840 * 2));           // 320 KB
    unsigned short* X1   = (unsigned short*)(base + alloc((size_t)R1 * 128 * 2)); // 2 MB
    if (ws_size < off) { fpno_guard<<<1, 64, 0, stream>>>(2048.0f, out); return; }

    const void* par  = d_in[0];
    const void* x    = d_in[1];
    const void* pos  = d_in[2];
    const void* xs1  = d_in[4];
    const void* pos1 = d_in[5];
    const void* xs0  = d_in[7];
    const void* pos0 = d_in[8];
    const int*  bt0  = (const int*)d_in[9];
    const void *W0a = d_in[10], *b0a = d_in[11], *W0b = d_in[12], *b0b = d_in[13];
    const void *Wp0 = d_in[14], *bp0 = d_in[15];
    const void *W1a = d_in[16], *b1a = d_in[17], *W1b = d_in[18], *b1b = d_in[19];
    const void *Wp1 = d_in[20], *bp1 = d_in[21];

    // PHASE 1: wconv(frag-order) | gates | layer-1 kNN | bins | tail
    fpno_p1<<<714, 512, 0, stream>>>(
        (const unsigned int*)pos, pos, pos1, pos0,
        W0a, W0b, W1a, W1b, par, Wp0, bp0, Wp1, bp1, bt0,
        flag, WT, g0, g1, i1d, w1d, ptsG, cstG, ptsT, cstT, out);

    // PHASE 2: fused layer-1 MLP 16-row slabs (512 blocks) | layer-2 kNN (1024)
    fpno_p2<<<1536, 256, 0, stream>>>(
        x, xs1, WT, b0a, b0b, g0, i1d, w1d,
        ptsG, cstG, ptsT, flag, X1, i0d, w0d);

    // PHASE 3: fused layer-2 MLP 16-row slabs -> fp32 out  (2048 blocks)
    fpno_p3<<<2048, 256, 0, stream>>>(
        X1, xs0, WT, b1a, b1b, g1, i0d, w0d, flag, out);
}